// Round 4
// baseline (221.962 us; speedup 1.0000x reference)
//
#include <hip/hip_runtime.h>

// Problem constants (T=512, B=16 -> 8192 tokens), all tensors float32
#define NTOK 8192
#define CDIM 512
#define NB   8
#define RD   64
#define OD   512

typedef unsigned char  u8;
typedef unsigned int   u32;
typedef unsigned short u16;

// workspace layout (bytes)
#define WS_Q      0          // 8192 u8
#define WS_COUNTS 8192       // 256 u32
#define WS_CURSOR 9216       // 256 u32
#define WS_OFF    10240      // 257 u32
#define WS_LIST   11520      // 8192 u16
#define WS_V      28672      // 8192*64 f32 (16B aligned)
#define WS_NEED   (WS_V + NTOK * RD * 4)

// ---------------------------------------------------------------------------
// init: zero the per-code counters (ws is poisoned 0xAA before every launch)
// ---------------------------------------------------------------------------
__global__ __launch_bounds__(256) void kInit(u32* __restrict__ counts) {
    counts[threadIdx.x] = 0u;
}

// ---------------------------------------------------------------------------
// Phase A. Grid = 640 blocks x 256 threads.
//  blocks 0..511: v = pw_w1 @ x. lane = token (64 tokens/block group),
//    block b: token-group b>>2, row-group b&3 (16 rows; wave w owns 4 rows).
//    w1 rows via wave-uniform (scalar-path) loads; x via per-lane float4
//    (64 lines/wave, L1-resident across k). No LDS, no barriers.
//  blocks 512..639: logits, f64 accumulation (bit = sign(k), sign-critical).
//    lane = token, wave w owns bits 2w, 2w+1; ballot -> per-token code;
//    also bumps counts[q] for the bucket sort.
// ---------------------------------------------------------------------------
__global__ __launch_bounds__(256) void kA(
    const float* __restrict__ x, const float* __restrict__ map_w,
    const float* __restrict__ map_b, const float* __restrict__ w1,
    u8* __restrict__ q_out, float* __restrict__ v_out,
    u32* __restrict__ counts, float* __restrict__ loss_out)
{
    const int t    = threadIdx.x;
    const int lane = t & 63;
    const int wv   = __builtin_amdgcn_readfirstlane(t >> 6);
    const int b    = blockIdx.x;

    if (b < 512) {
        const int tg  = b >> 2;
        const int rg  = b & 3;
        const int tok = tg * 64 + lane;
        const int r0  = __builtin_amdgcn_readfirstlane(rg * 16 + wv * 4);
        const float4* __restrict__ x4 = (const float4*)x + (size_t)tok * (CDIM / 4);
        const float4* __restrict__ w4 = (const float4*)w1;
        float a0 = 0.f, a1 = 0.f, a2 = 0.f, a3 = 0.f;
        #pragma unroll 4
        for (int k = 0; k < CDIM / 4; ++k) {
            float4 xv = x4[k];
            float4 w0 = w4[(size_t)(r0 + 0) * (CDIM / 4) + k];
            float4 w1v = w4[(size_t)(r0 + 1) * (CDIM / 4) + k];
            float4 w2 = w4[(size_t)(r0 + 2) * (CDIM / 4) + k];
            float4 w3 = w4[(size_t)(r0 + 3) * (CDIM / 4) + k];
            a0 += w0.x * xv.x + w0.y * xv.y + w0.z * xv.z + w0.w * xv.w;
            a1 += w1v.x * xv.x + w1v.y * xv.y + w1v.z * xv.z + w1v.w * xv.w;
            a2 += w2.x * xv.x + w2.y * xv.y + w2.z * xv.z + w2.w * xv.w;
            a3 += w3.x * xv.x + w3.y * xv.y + w3.z * xv.z + w3.w * xv.w;
        }
        float4 o = make_float4(a0, a1, a2, a3);
        *((float4*)(v_out + (size_t)tok * RD + r0)) = o;
    } else {
        const int tg  = b - 512;
        const int tok = tg * 64 + lane;
        __shared__ u32 qs[64];
        if (t < 64) qs[t] = 0u;
        __syncthreads();

        const int b0 = __builtin_amdgcn_readfirstlane(2 * wv);
        const int b1 = b0 + 1;
        const float4* __restrict__ x4 = (const float4*)x + (size_t)tok * (CDIM / 4);
        const float4* __restrict__ m4 = (const float4*)map_w;
        double s0 = 0.0, s1 = 0.0;
        for (int k = 0; k < CDIM / 4; ++k) {
            float4 xv = x4[k];
            float4 m0 = m4[(size_t)b0 * (CDIM / 4) + k];
            float4 m1 = m4[(size_t)b1 * (CDIM / 4) + k];
            s0 += (double)m0.x * (double)xv.x + (double)m0.y * (double)xv.y
                + (double)m0.z * (double)xv.z + (double)m0.w * (double)xv.w;
            s1 += (double)m1.x * (double)xv.x + (double)m1.y * (double)xv.y
                + (double)m1.z * (double)xv.z + (double)m1.w * (double)xv.w;
        }
        s0 += (double)map_b[b0];
        s1 += (double)map_b[b1];
        unsigned long long m0 = __ballot(s0 > 0.0);
        unsigned long long m1 = __ballot(s1 > 0.0);
        u32 bits = (u32)(((m0 >> lane) & 1ull) | (((m1 >> lane) & 1ull) << 1)) << (2 * wv);
        if (bits) atomicOr(&qs[lane], bits);
        __syncthreads();
        if (t < 64) {
            u32 q = qs[t];
            q_out[tok] = (u8)q;
            atomicAdd(&counts[q], 1u);
        }
        if (b == 512 && t == 0) loss_out[0] = 0.0f;   // loss output = 0
    }
}

// ---------------------------------------------------------------------------
// prefix: exclusive scan of counts -> off[0..256], cursor = off
// ---------------------------------------------------------------------------
__global__ __launch_bounds__(256) void kPrefix(
    const u32* __restrict__ counts, u32* __restrict__ off, u32* __restrict__ cursor)
{
    __shared__ u32 s[256];
    const int t = threadIdx.x;
    u32 c = counts[t];
    s[t] = c;
    __syncthreads();
    for (int d = 1; d < 256; d <<= 1) {
        u32 v = (t >= d) ? s[t - d] : 0u;
        __syncthreads();
        s[t] += v;
        __syncthreads();
    }
    u32 excl = s[t] - c;
    off[t] = excl;
    cursor[t] = excl;
    if (t == 255) off[256] = s[255];
}

// ---------------------------------------------------------------------------
// scatter: tokens into per-code contiguous lists
// ---------------------------------------------------------------------------
__global__ __launch_bounds__(256) void kScatter(
    const u8* __restrict__ q_arr, u32* __restrict__ cursor, u16* __restrict__ list)
{
    const int tok = blockIdx.x * 256 + threadIdx.x;
    u32 pos = atomicAdd(&cursor[q_arr[tok]], 1u);
    list[pos] = (u16)tok;
}

// ---------------------------------------------------------------------------
// Phase B: 512 blocks x 256 threads. block = (code q = b>>1, output half
// b&1). Thread t owns output o; fused weights w21[q,o,:]+w22[255-q,o,:]
// in 64 VGPRs; v rows read through uniform (scalar-path) addresses.
// No LDS in the hot loop.
// ---------------------------------------------------------------------------
__global__ __launch_bounds__(256) void kB(
    const u16* __restrict__ list, const u32* __restrict__ off,
    const float* __restrict__ v_arr,
    const float* __restrict__ w21, const float* __restrict__ w22,
    const float* __restrict__ pwB, float* __restrict__ y)
{
    const int q  = blockIdx.x >> 1;
    const int oh = blockIdx.x & 1;
    const int o  = oh * 256 + threadIdx.x;
    const u32 lo = off[q], hi = off[q + 1];
    if (lo == hi) return;

    const float4* __restrict__ pa = (const float4*)(w21 + ((size_t)q * OD + o) * RD);
    const float4* __restrict__ pb = (const float4*)(w22 + ((size_t)(255 - q) * OD + o) * RD);
    float w[RD];
    #pragma unroll
    for (int j = 0; j < RD / 4; ++j) {
        float4 a = pa[j], bb = pb[j];
        w[j * 4 + 0] = a.x + bb.x;
        w[j * 4 + 1] = a.y + bb.y;
        w[j * 4 + 2] = a.z + bb.z;
        w[j * 4 + 3] = a.w + bb.w;
    }
    const float bias = pwB[o];

    for (u32 i = lo; i < hi; ++i) {
        const int tok = __builtin_amdgcn_readfirstlane((int)list[i]);
        const float4* __restrict__ vr = (const float4*)(v_arr + (size_t)tok * RD);
        float acc = bias;
        #pragma unroll
        for (int j = 0; j < RD / 4; ++j) {
            float4 vv = vr[j];
            acc += w[j * 4 + 0] * vv.x + w[j * 4 + 1] * vv.y
                 + w[j * 4 + 2] * vv.z + w[j * 4 + 3] * vv.w;
        }
        y[(size_t)tok * OD + o] = acc;
    }
}

// ---------------------------------------------------------------------------
// Fallback (ws too small): workspace-free, one block per token.
// ---------------------------------------------------------------------------
__global__ __launch_bounds__(256) void mono(
    const float* __restrict__ x, const float* __restrict__ map_w,
    const float* __restrict__ map_b, const float* __restrict__ w1,
    const float* __restrict__ w21, const float* __restrict__ w22,
    const float* __restrict__ pwB, float* __restrict__ y)
{
    const int tok = blockIdx.x;
    const int t   = threadIdx.x;
    __shared__ float xsh[CDIM];
    __shared__ float vsh[RD];
    __shared__ int qsh;

    if (t == 0) qsh = 0;
    for (int i = t; i < CDIM; i += 256) xsh[i] = x[(size_t)tok * CDIM + i];
    __syncthreads();

    if (t < NB) {
        double a = 0.0;
        const float* mrow = map_w + (size_t)t * CDIM;
        for (int j = 0; j < CDIM; ++j) a += (double)mrow[j] * (double)xsh[j];
        a += (double)map_b[t];
        if (a > 0.0) atomicOr(&qsh, 1 << t);
    }
    if (t < RD) {
        const float* wrow = w1 + (size_t)t * CDIM;
        float acc = 0.f;
        for (int j = 0; j < CDIM; ++j) acc += wrow[j] * xsh[j];
        vsh[t] = acc;
    }
    __syncthreads();

    const int q = qsh;
    for (int o = t; o < OD; o += 256) {
        const float* pa = w21 + (size_t)q * (OD * RD) + (size_t)o * RD;
        const float* pb = w22 + (size_t)(255 - q) * (OD * RD) + (size_t)o * RD;
        float acc = pwB[o];
        for (int r = 0; r < RD; ++r) acc += (pa[r] + pb[r]) * vsh[r];
        y[(size_t)tok * OD + o] = acc;
    }
    if (tok == 0 && t == 0) y[(size_t)NTOK * OD] = 0.0f;
}

extern "C" void kernel_launch(void* const* d_in, const int* in_sizes, int n_in,
                              void* d_out, int out_size, void* d_ws, size_t ws_size,
                              hipStream_t stream) {
    const float* x     = (const float*)d_in[0];
    // d_in[1] = key: unused by the forward pass
    const float* map_w = (const float*)d_in[2];
    const float* map_b = (const float*)d_in[3];
    const float* w1    = (const float*)d_in[4];
    const float* w21   = (const float*)d_in[5];
    const float* w22   = (const float*)d_in[6];
    const float* pwB   = (const float*)d_in[7];
    float* out = (float*)d_out;

    if (ws_size >= (size_t)WS_NEED) {
        char* ws = (char*)d_ws;
        u8*    q_ws   = (u8*)(ws + WS_Q);
        u32*   counts = (u32*)(ws + WS_COUNTS);
        u32*   cursor = (u32*)(ws + WS_CURSOR);
        u32*   off    = (u32*)(ws + WS_OFF);
        u16*   list   = (u16*)(ws + WS_LIST);
        float* v_ws   = (float*)(ws + WS_V);

        kInit<<<1, 256, 0, stream>>>(counts);
        kA<<<640, 256, 0, stream>>>(x, map_w, map_b, w1, q_ws, v_ws, counts,
                                    out + (size_t)NTOK * OD);
        kPrefix<<<1, 256, 0, stream>>>(counts, off, cursor);
        kScatter<<<NTOK / 256, 256, 0, stream>>>(q_ws, cursor, list);
        kB<<<512, 256, 0, stream>>>(list, off, v_ws, w21, w22, pwB, out);
    } else {
        mono<<<NTOK, 256, 0, stream>>>(x, map_w, map_b, w1, w21, w22, pwB, out);
    }
}